// Round 1
// baseline (358.135 us; speedup 1.0000x reference)
//
#include <hip/hip_runtime.h>
#include <hip/hip_cooperative_groups.h>

namespace cg = cooperative_groups;

#define N_NODES  100000
#define N_EDGES  3200000
#define NB       8                    // buckets
#define BN       12544                // nodes per bucket (8*12544 >= 100000)
#define NBLK     256                  // grid = 256 blocks = 1/CU (cooperative)
#define THR      1024
#define QPB      (N_EDGES / NBLK / 4) // 3125 uint4 quads per scan-block
#define CAP      2048                 // per (scan-block,bucket) region capacity (mean ~1563)
#define SA       32                   // acc blocks per bucket
#define SPS      (NBLK / SA)          // 8 scan-block regions per acc block

// ws layout (4-byte words):
//   cnt[NBLK*NB] | pedge[NBLK*NB*CAP] | partials[NBLK*BN] | dinv[N] | xs[N] | us[N] | uself[N]
//   total ~31.2 MB

__device__ __forceinline__ float sum_partials(const float* __restrict__ partials,
                                              int bu, int l) {
    const float* pp = partials + (size_t)(bu * SA) * BN + l;
    float s = 0.f;
    #pragma unroll
    for (int k = 0; k < SA; ++k) s += pp[(size_t)k * BN];
    return s;
}

// scatter one value-class from this block's assigned regions into LDS, dump partials
__device__ __forceinline__ void acc_phase(const unsigned* __restrict__ pedge,
        const unsigned* __restrict__ cnt, const float* __restrict__ vals,
        float* __restrict__ partials, float* facc, int degmode) {
    const int tid = threadIdx.x, a = blockIdx.x;
    const int bu = a >> 5, sub = a & 31;
    for (int i = tid; i < BN; i += THR) facc[i] = 0.f;
    __syncthreads();
    for (int s = 0; s < SPS; ++s) {
        const int r = (sub * SPS + s) * NB + bu;
        const unsigned n = cnt[r];
        const unsigned* reg = pedge + (size_t)r * CAP;
        if (degmode) {
            for (unsigned j = tid; j < n; j += THR)
                atomicAdd(&facc[reg[j] >> 17], 1.f);
        } else {
            for (unsigned j = tid; j < n; j += THR) {
                const unsigned w = reg[j];
                atomicAdd(&facc[w >> 17], vals[w & 0x1FFFFu]);
            }
        }
    }
    __syncthreads();
    float4* po = (float4*)(partials + (size_t)a * BN);
    const float4* fi = (const float4*)facc;
    for (int i = tid; i < BN / 4; i += THR) po[i] = fi[i];
}

__global__ __launch_bounds__(THR, 4) void k_fused(
        const float* __restrict__ x, const int* __restrict__ ei,
        const float* __restrict__ W1, const float* __restrict__ b1,
        const float* __restrict__ W2, const float* __restrict__ b2,
        const float* __restrict__ Wl, const float* __restrict__ bl,
        unsigned* __restrict__ cnt, unsigned* __restrict__ pedge,
        float* __restrict__ partials, float* __restrict__ dinv,
        float* __restrict__ xs, float* __restrict__ us,
        float* __restrict__ uself, float* __restrict__ out)
{
    cg::grid_group grid = cg::this_grid();
    __shared__ __align__(16) unsigned stag[BN];   // staging; reused as f32 facc
    __shared__ unsigned bcnt[NB], bbase[NB], bcur[NB];
    __shared__ float v2l[16];
    float* const facc = (float*)stag;
    const int tid = threadIdx.x;
    const int blk = blockIdx.x;

    // ---- constants: v2l[c] = (W2 @ Wl)[c] (same accumulation order as before)
    if (tid < 16) {
        float vcc = 0.f;
        #pragma unroll
        for (int k = 0; k < 16; ++k) vcc += W2[tid * 16 + k] * Wl[k];
        v2l[tid] = vcc;
    }
    if (tid < NB) bcnt[tid] = 0u;
    __syncthreads();

    // ---- P1: single-read edge routing (count -> prefix -> place -> flush) ---
    const uint4* s4 = (const uint4*)ei;
    const uint4* d4 = (const uint4*)(ei + N_EDGES);
    const int q0 = blk * QPB;
    uint4 dq[4], sq[4];
    #pragma unroll
    for (int i = 0; i < 4; ++i) {
        const int q = tid + i * THR;
        if (q < QPB) { dq[i] = d4[q0 + q]; sq[i] = s4[q0 + q]; }
    }
    #pragma unroll
    for (int i = 0; i < 4; ++i) {
        const int q = tid + i * THR;
        if (q < QPB) {
            const unsigned dd[4] = { dq[i].x, dq[i].y, dq[i].z, dq[i].w };
            #pragma unroll
            for (int k = 0; k < 4; ++k) atomicAdd(&bcnt[dd[k] / BN], 1u);
        }
    }
    __syncthreads();
    if (tid == 0) {
        unsigned run = 0;
        #pragma unroll
        for (int b = 0; b < NB; ++b) { bbase[b] = run; bcur[b] = run; run += bcnt[b]; }
    }
    __syncthreads();
    #pragma unroll
    for (int i = 0; i < 4; ++i) {
        const int q = tid + i * THR;
        if (q < QPB) {
            const unsigned dd[4] = { dq[i].x, dq[i].y, dq[i].z, dq[i].w };
            const unsigned ss[4] = { sq[i].x, sq[i].y, sq[i].z, sq[i].w };
            #pragma unroll
            for (int k = 0; k < 4; ++k) {
                const unsigned d = dd[k];
                const unsigned b = d / BN;
                const unsigned slot = atomicAdd(&bcur[b], 1u);
                if (slot < (unsigned)(BN)) stag[slot] = ss[k] | ((d - b * BN) << 17);
            }
        }
    }
    __syncthreads();
    #pragma unroll
    for (int b = 0; b < NB; ++b) {
        const unsigned n = bcnt[b] < CAP ? bcnt[b] : CAP;
        const unsigned base = bbase[b];
        unsigned* reg = pedge + ((size_t)blk * NB + b) * CAP;
        for (unsigned j = tid; j < n; j += THR) reg[j] = stag[base + j];
    }
    if (tid < NB) cnt[blk * NB + tid] = bcnt[tid] < CAP ? bcnt[tid] : CAP;
    grid.sync();

    // ---- P2: degree scatter -> partials ------------------------------------
    acc_phase(pedge, cnt, (const float*)0, partials, facc, 1);
    grid.sync();

    const int g = blk * THR + tid;
    int bu_g = 0, l_g = 0;
    if (g < N_NODES) { bu_g = g / BN; l_g = g - bu_g * BN; }

    // ---- P3: deg -> dinv, xs ------------------------------------------------
    if (g < N_NODES) {
        const float deg = sum_partials(partials, bu_g, l_g);
        const float di = rsqrtf(deg + 1.f);          // + self loop
        dinv[g] = di;
        xs[g] = x[g] * di;
    }
    grid.sync();

    // ---- P4: scatter xs -----------------------------------------------------
    acc_phase(pedge, cnt, xs, partials, facc, 0);
    grid.sync();

    // ---- P5: layer1 + fold layer2 weights -> us, uself ----------------------
    if (g < N_NODES) {
        const float sum = sum_partials(partials, bu_g, l_g);
        const float di = dinv[g];
        const float s1 = di * sum + x[g] * di * di;
        float u = 0.f;
        #pragma unroll
        for (int c = 0; c < 16; ++c)
            u += fmaxf(W1[c] * s1 + b1[c], 0.f) * v2l[c];
        us[g] = u * di;
        uself[g] = u * di * di;
    }
    grid.sync();

    // ---- P6: scatter us -----------------------------------------------------
    acc_phase(pedge, cnt, us, partials, facc, 0);
    grid.sync();

    // ---- P7: epilogue -------------------------------------------------------
    if (g < N_NODES) {
        const float sum = sum_partials(partials, bu_g, l_g);
        float vcb = bl[0];
        #pragma unroll
        for (int c = 0; c < 16; ++c) vcb += b2[c] * v2l[c];
        out[g] = dinv[g] * sum + uself[g] + vcb;
    }
}

extern "C" void kernel_launch(void* const* d_in, const int* in_sizes, int n_in,
                              void* d_out, int out_size, void* d_ws, size_t ws_size,
                              hipStream_t stream) {
    const float* x  = (const float*)d_in[0];
    const int*   ei = (const int*)d_in[1];
    const float* W1 = (const float*)d_in[2];
    const float* b1 = (const float*)d_in[3];
    const float* W2 = (const float*)d_in[4];
    const float* b2 = (const float*)d_in[5];
    const float* Wl = (const float*)d_in[6];
    const float* bl = (const float*)d_in[7];
    float* out = (float*)d_out;

    unsigned* cnt      = (unsigned*)d_ws;
    unsigned* pedge    = cnt + NBLK * NB;
    float*    partials = (float*)(pedge + (size_t)NBLK * NB * CAP);
    float*    dinv     = partials + (size_t)NBLK * BN;
    float*    xs       = dinv + N_NODES;
    float*    us       = xs + N_NODES;
    float*    uself    = us + N_NODES;

    void* args[] = { (void*)&x, (void*)&ei, (void*)&W1, (void*)&b1,
                     (void*)&W2, (void*)&b2, (void*)&Wl, (void*)&bl,
                     (void*)&cnt, (void*)&pedge, (void*)&partials, (void*)&dinv,
                     (void*)&xs, (void*)&us, (void*)&uself, (void*)&out };
    hipLaunchCooperativeKernel((const void*)k_fused, dim3(NBLK), dim3(THR),
                               args, 0, stream);
}

// Round 2
// 197.394 us; speedup vs baseline: 1.8143x; 1.8143x over previous
//
#include <hip/hip_runtime.h>

#define N_NODES  100000
#define N_EDGES  3200000
#define NB       8                    // buckets
#define BN       12544                // nodes per bucket (8*12544 >= 100000)
#define NBLK     256                  // routing blocks
#define THR      1024
#define QPB      (N_EDGES / NBLK / 4) // 3125 uint4 quads per routing block
#define CAP      2048                 // per (block,bucket) region cap (mean 1562, sigma 37)
#define SA       32                   // acc blocks per bucket
#define SPS      (NBLK / SA)          // 8 routing-block regions per acc block
#define GA       (NB * SA)            // 256 acc blocks
#define REDB     ((N_NODES + THR - 1) / THR)

// ws layout (4-byte words):
//   cnt[NBLK*NB] | pedge[NBLK*NB*CAP] | partials[GA*BN] | dinv[N] | xs[N] | us[N] | uself[N]

// ---- K1: single-read edge routing (count -> prefix -> place -> flush) -------
__global__ __launch_bounds__(THR) void k_route(
        const int* __restrict__ ei, unsigned* __restrict__ cnt,
        unsigned* __restrict__ pedge) {
    __shared__ __align__(16) unsigned stag[BN];   // bucket-sorted edges of this block
    __shared__ unsigned bcnt[NB], bbase[NB], bcur[NB];
    const int tid = threadIdx.x, blk = blockIdx.x;
    if (tid < NB) bcnt[tid] = 0u;
    __syncthreads();

    const uint4* s4 = (const uint4*)ei;
    const uint4* d4 = (const uint4*)(ei + N_EDGES);
    const int q0 = blk * QPB;
    uint4 dq[4], sq[4];
    #pragma unroll
    for (int i = 0; i < 4; ++i) {
        const int q = tid + i * THR;
        if (q < QPB) { dq[i] = d4[q0 + q]; sq[i] = s4[q0 + q]; }
    }

    // per-thread byte-packed bucket histogram (max 16 edges/thread fits u8)
    unsigned c01 = 0, c23 = 0;
    #pragma unroll
    for (int i = 0; i < 4; ++i) {
        const int q = tid + i * THR;
        if (q < QPB) {
            const unsigned dd[4] = { dq[i].x, dq[i].y, dq[i].z, dq[i].w };
            #pragma unroll
            for (int k = 0; k < 4; ++k) {
                const unsigned b = dd[k] / BN;
                if (b < 4) c01 += 1u << (8 * b);
                else       c23 += 1u << (8 * (b - 4));
            }
        }
    }
    #pragma unroll
    for (int b = 0; b < 4; ++b) {
        const unsigned v0 = (c01 >> (8 * b)) & 0xFFu;
        const unsigned v1 = (c23 >> (8 * b)) & 0xFFu;
        if (v0) atomicAdd(&bcnt[b], v0);
        if (v1) atomicAdd(&bcnt[b + 4], v1);
    }
    __syncthreads();
    if (tid == 0) {
        unsigned run = 0;
        #pragma unroll
        for (int b = 0; b < NB; ++b) { bbase[b] = run; bcur[b] = run; run += bcnt[b]; }
    }
    __syncthreads();

    // place (total edges/block = 12500 < BN, so stag never overflows)
    #pragma unroll
    for (int i = 0; i < 4; ++i) {
        const int q = tid + i * THR;
        if (q < QPB) {
            const unsigned dd[4] = { dq[i].x, dq[i].y, dq[i].z, dq[i].w };
            const unsigned ss[4] = { sq[i].x, sq[i].y, sq[i].z, sq[i].w };
            #pragma unroll
            for (int k = 0; k < 4; ++k) {
                const unsigned d = dd[k];
                const unsigned b = d / BN;
                const unsigned slot = atomicAdd(&bcur[b], 1u);
                stag[slot] = ss[k] | ((d - b * BN) << 17);
            }
        }
    }
    __syncthreads();

    // coalesced flush per bucket region
    #pragma unroll
    for (int b = 0; b < NB; ++b) {
        const unsigned n = bcnt[b] < CAP ? bcnt[b] : CAP;
        const unsigned base = bbase[b];
        unsigned* reg = pedge + ((size_t)(blk * NB + b)) * CAP;
        for (unsigned j = tid; j < n; j += THR) reg[j] = stag[base + j];
    }
    if (tid < NB) cnt[blk * NB + tid] = bcnt[tid] < CAP ? bcnt[tid] : CAP;
}

// ---- K2/K4/K6: scatter one value-class into LDS bucket image ---------------
__global__ __launch_bounds__(THR) void k_acc(
        const unsigned* __restrict__ pedge, const unsigned* __restrict__ cnt,
        const float* __restrict__ vals, float* __restrict__ partials,
        const int degmode) {
    __shared__ __align__(16) float facc[BN];
    const int tid = threadIdx.x;
    const int bu = blockIdx.x / SA, sub = blockIdx.x % SA;
    for (int i = tid; i < BN; i += THR) facc[i] = 0.f;
    __syncthreads();
    for (int s = 0; s < SPS; ++s) {
        const int r = (sub * SPS + s) * NB + bu;
        const unsigned n = cnt[r];
        const unsigned* reg = pedge + (size_t)r * CAP;
        if (degmode) {
            for (unsigned j = tid; j < n; j += THR)
                atomicAdd(&facc[reg[j] >> 17], 1.f);
        } else {
            for (unsigned j = tid; j < n; j += THR) {
                const unsigned w = reg[j];
                atomicAdd(&facc[w >> 17], vals[w & 0x1FFFFu]);
            }
        }
    }
    __syncthreads();
    float4* po = (float4*)(partials + (size_t)blockIdx.x * BN);
    const float4* fi = (const float4*)facc;
    for (int i = tid; i < BN / 4; i += THR) po[i] = fi[i];
}

// ---- partial reduction helper (SA slices, coalesced across threads) ---------
__device__ __forceinline__ float sum_partials(const float* __restrict__ partials,
                                              int g) {
    const int bu = g / BN, l = g - bu * BN;
    const float* pp = partials + (size_t)(bu * SA) * BN + l;
    float s = 0.f;
    #pragma unroll
    for (int k = 0; k < SA; ++k) s += pp[(size_t)k * BN];
    return s;
}

// ---- K3: deg -> dinv, xs ----------------------------------------------------
__global__ __launch_bounds__(THR) void k_red1(const float* __restrict__ x,
        const float* __restrict__ partials,
        float* __restrict__ dinv, float* __restrict__ xs) {
    const int g = blockIdx.x * THR + threadIdx.x;
    if (g >= N_NODES) return;
    const float deg = sum_partials(partials, g);   // exact integer counts in f32
    const float di = rsqrtf(deg + 1.f);            // + self loop
    dinv[g] = di;
    xs[g] = x[g] * di;
}

// ---- K5: layer1 + folded layer2 weights -> us, uself ------------------------
__global__ __launch_bounds__(THR) void k_red2(const float* __restrict__ x,
        const float* __restrict__ partials, const float* __restrict__ dinv,
        const float* __restrict__ W1, const float* __restrict__ b1,
        const float* __restrict__ W2, const float* __restrict__ Wl,
        float* __restrict__ us, float* __restrict__ uself) {
    const int g = blockIdx.x * THR + threadIdx.x;
    if (g >= N_NODES) return;
    const float sum = sum_partials(partials, g);
    const float di = dinv[g];
    const float s1 = di * sum + x[g] * di * di;
    float u = 0.f;
    #pragma unroll
    for (int c = 0; c < 16; ++c) {
        float vcc = 0.f;
        #pragma unroll
        for (int k = 0; k < 16; ++k) vcc += W2[c * 16 + k] * Wl[k];  // (W2@Wl)[c]
        u += fmaxf(W1[c] * s1 + b1[c], 0.f) * vcc;
    }
    us[g] = u * di;
    uself[g] = u * di * di;
}

// ---- K7: epilogue -----------------------------------------------------------
__global__ __launch_bounds__(THR) void k_red3(const float* __restrict__ partials,
        const float* __restrict__ dinv, const float* __restrict__ uself,
        const float* __restrict__ W2, const float* __restrict__ b2,
        const float* __restrict__ Wl, const float* __restrict__ bl,
        float* __restrict__ out) {
    const int g = blockIdx.x * THR + threadIdx.x;
    if (g >= N_NODES) return;
    const float sum = sum_partials(partials, g);
    float vcb = bl[0];
    #pragma unroll
    for (int c = 0; c < 16; ++c) {
        float vcc = 0.f;
        #pragma unroll
        for (int k = 0; k < 16; ++k) vcc += W2[c * 16 + k] * Wl[k];
        vcb += b2[c] * vcc;
    }
    out[g] = dinv[g] * sum + uself[g] + vcb;
}

extern "C" void kernel_launch(void* const* d_in, const int* in_sizes, int n_in,
                              void* d_out, int out_size, void* d_ws, size_t ws_size,
                              hipStream_t stream) {
    const float* x  = (const float*)d_in[0];
    const int*   ei = (const int*)d_in[1];
    const float* W1 = (const float*)d_in[2];
    const float* b1 = (const float*)d_in[3];
    const float* W2 = (const float*)d_in[4];
    const float* b2 = (const float*)d_in[5];
    const float* Wl = (const float*)d_in[6];
    const float* bl = (const float*)d_in[7];
    float* out = (float*)d_out;

    unsigned* cnt      = (unsigned*)d_ws;
    unsigned* pedge    = cnt + NBLK * NB;
    float*    partials = (float*)(pedge + (size_t)NBLK * NB * CAP);
    float*    dinv     = partials + (size_t)GA * BN;
    float*    xs       = dinv + N_NODES;
    float*    us       = xs + N_NODES;
    float*    uself    = us + N_NODES;

    k_route<<<NBLK, THR, 0, stream>>>(ei, cnt, pedge);
    k_acc  <<<GA,   THR, 0, stream>>>(pedge, cnt, (const float*)0, partials, 1);
    k_red1 <<<REDB, THR, 0, stream>>>(x, partials, dinv, xs);
    k_acc  <<<GA,   THR, 0, stream>>>(pedge, cnt, xs, partials, 0);
    k_red2 <<<REDB, THR, 0, stream>>>(x, partials, dinv, W1, b1, W2, Wl, us, uself);
    k_acc  <<<GA,   THR, 0, stream>>>(pedge, cnt, us, partials, 0);
    k_red3 <<<REDB, THR, 0, stream>>>(partials, dinv, uself, W2, b2, Wl, bl, out);
}

// Round 3
// 189.555 us; speedup vs baseline: 1.8893x; 1.0414x over previous
//
#include <hip/hip_runtime.h>

#define N_NODES  100000
#define N_EDGES  3200000
#define NB       8                    // buckets
#define BN       12544                // nodes per bucket (8*12544 >= 100000)
#define BNH      (BN / 2)             // 6272 packed u16-pair words
#define NRT      256                  // routing blocks
#define NDG      64                   // degree blocks (8 buckets x 8 slices)
#define DSL      8                    // degree slices per bucket
#define THR      1024
#define QPB      (N_EDGES / NRT / 4)  // 3125 uint4 quads per routing block
#define QDS      (N_EDGES / DSL / 4)  // 100000 quads per degree slice
#define CAP      2048                 // per (block,bucket) region cap (mean 1562, sigma 37)
#define SA       32                   // acc blocks per bucket
#define SPS      (NRT / SA)           // 8 routing-block regions per acc block
#define GA       (NB * SA)            // 256 acc blocks
#define TRD      256                  // reduction block size

// ws (u32 words): cnt[NRT*NB] | pedge[NRT*NB*CAP] | partials f32[GA*BN]
//                 | pdeg u32[NDG*BNH] | dinv[N] | xs[N] | us[N] | uself[N]

// ---- K1: block-role fused single-read routing + dst-degree histograms ------
__global__ __launch_bounds__(THR) void k_route_deg(
        const int* __restrict__ ei, unsigned* __restrict__ cnt,
        unsigned* __restrict__ pedge, unsigned* __restrict__ pdeg) {
    __shared__ __align__(16) unsigned smem[BN];   // stag (route) / packed hist (deg)
    __shared__ unsigned bcnt[NB], bbase[NB], bcur[NB];
    const int tid = threadIdx.x;
    const uint4* d4 = (const uint4*)(ei + N_EDGES);

    if (blockIdx.x < NDG) {
        // ---- degree role: bucket-owned u16-packed histogram of one dst slice
        const int bu = blockIdx.x >> 3, s = blockIdx.x & 7;
        for (int i = tid; i < BNH; i += THR) smem[i] = 0u;
        __syncthreads();
        const unsigned base_node = (unsigned)bu * BN;
        const int q1 = (s + 1) * QDS;
        #pragma unroll 2
        for (int q = s * QDS + tid; q < q1; q += THR) {
            const uint4 dv = d4[q];
            const unsigned dd[4] = { dv.x, dv.y, dv.z, dv.w };
            #pragma unroll
            for (int k = 0; k < 4; ++k) {
                const unsigned d = dd[k];
                if (d / BN == (unsigned)bu) {
                    const unsigned dl = d - base_node;
                    atomicAdd(&smem[dl >> 1], 1u << ((dl & 1) << 4));
                }
            }
        }
        __syncthreads();
        uint4* po = (uint4*)(pdeg + (size_t)blockIdx.x * BNH);
        const uint4* fi = (const uint4*)smem;
        for (int i = tid; i < BNH / 4; i += THR) po[i] = fi[i];
        return;
    }

    // ---- routing role: count -> prefix -> place -> coalesced flush ---------
    const int blk = blockIdx.x - NDG;
    if (tid < NB) bcnt[tid] = 0u;
    __syncthreads();

    const uint4* s4 = (const uint4*)ei;
    const int q0 = blk * QPB;
    uint4 dq[4], sq[4];
    #pragma unroll
    for (int i = 0; i < 4; ++i) {
        const int q = tid + i * THR;
        if (q < QPB) { dq[i] = d4[q0 + q]; sq[i] = s4[q0 + q]; }
    }

    unsigned c01 = 0, c23 = 0;   // byte-packed per-thread bucket histogram
    #pragma unroll
    for (int i = 0; i < 4; ++i) {
        const int q = tid + i * THR;
        if (q < QPB) {
            const unsigned dd[4] = { dq[i].x, dq[i].y, dq[i].z, dq[i].w };
            #pragma unroll
            for (int k = 0; k < 4; ++k) {
                const unsigned b = dd[k] / BN;
                if (b < 4) c01 += 1u << (8 * b);
                else       c23 += 1u << (8 * (b - 4));
            }
        }
    }
    #pragma unroll
    for (int b = 0; b < 4; ++b) {
        const unsigned v0 = (c01 >> (8 * b)) & 0xFFu;
        const unsigned v1 = (c23 >> (8 * b)) & 0xFFu;
        if (v0) atomicAdd(&bcnt[b], v0);
        if (v1) atomicAdd(&bcnt[b + 4], v1);
    }
    __syncthreads();
    if (tid == 0) {
        unsigned run = 0;
        #pragma unroll
        for (int b = 0; b < NB; ++b) { bbase[b] = run; bcur[b] = run; run += bcnt[b]; }
    }
    __syncthreads();

    #pragma unroll
    for (int i = 0; i < 4; ++i) {
        const int q = tid + i * THR;
        if (q < QPB) {
            const unsigned dd[4] = { dq[i].x, dq[i].y, dq[i].z, dq[i].w };
            const unsigned ss[4] = { sq[i].x, sq[i].y, sq[i].z, sq[i].w };
            #pragma unroll
            for (int k = 0; k < 4; ++k) {
                const unsigned d = dd[k];
                const unsigned b = d / BN;
                const unsigned slot = atomicAdd(&bcur[b], 1u);
                smem[slot] = ss[k] | ((d - b * BN) << 17);   // total 12500 < BN
            }
        }
    }
    __syncthreads();

    #pragma unroll
    for (int b = 0; b < NB; ++b) {
        const unsigned n = bcnt[b] < CAP ? bcnt[b] : CAP;
        const unsigned base = bbase[b];
        unsigned* reg = pedge + ((size_t)(blk * NB + b)) * CAP;
        for (unsigned j = tid; j < n; j += THR) reg[j] = smem[base + j];
    }
    if (tid < NB) cnt[blk * NB + tid] = bcnt[tid] < CAP ? bcnt[tid] : CAP;
}

// ---- K3/K5: scatter one value-class into LDS bucket image (ILP-4 gathers) --
__global__ __launch_bounds__(THR) void k_acc(
        const unsigned* __restrict__ pedge, const unsigned* __restrict__ cnt,
        const float* __restrict__ vals, float* __restrict__ partials) {
    __shared__ __align__(16) float facc[BN];
    const int tid = threadIdx.x;
    const int bu = blockIdx.x / SA, sub = blockIdx.x % SA;
    for (int i = tid; i < BN / 4; i += THR)
        ((float4*)facc)[i] = make_float4(0.f, 0.f, 0.f, 0.f);
    __syncthreads();
    for (int s = 0; s < SPS; ++s) {
        const int r = (sub * SPS + s) * NB + bu;
        const unsigned n = cnt[r];
        const unsigned* reg = pedge + (size_t)r * CAP;
        const uint4* reg4 = (const uint4*)reg;
        const unsigned n4 = n >> 2;
        for (unsigned j = tid; j < n4; j += THR) {
            const uint4 w = reg4[j];
            const float v0 = vals[w.x & 0x1FFFFu];
            const float v1 = vals[w.y & 0x1FFFFu];
            const float v2 = vals[w.z & 0x1FFFFu];
            const float v3 = vals[w.w & 0x1FFFFu];
            atomicAdd(&facc[w.x >> 17], v0);
            atomicAdd(&facc[w.y >> 17], v1);
            atomicAdd(&facc[w.z >> 17], v2);
            atomicAdd(&facc[w.w >> 17], v3);
        }
        for (unsigned j = (n4 << 2) + tid; j < n; j += THR) {
            const unsigned w = reg[j];
            atomicAdd(&facc[w >> 17], vals[w & 0x1FFFFu]);
        }
    }
    __syncthreads();
    float4* po = (float4*)(partials + (size_t)blockIdx.x * BN);
    const float4* fi = (const float4*)facc;
    for (int i = tid; i < BN / 4; i += THR) po[i] = fi[i];
}

// ---- f32 partial reduction (SA slices, coalesced) ---------------------------
__device__ __forceinline__ float sum_partials(const float* __restrict__ partials,
                                              int g) {
    const int bu = g / BN, l = g - bu * BN;
    const float* pp = partials + (size_t)(bu * SA) * BN + l;
    float s = 0.f;
    #pragma unroll
    for (int k = 0; k < SA; ++k) s += pp[(size_t)k * BN];
    return s;
}

// ---- K2: packed u16 deg partials -> dinv, xs (2 nodes/thread) --------------
__global__ __launch_bounds__(TRD) void k_red1(const float* __restrict__ x,
        const unsigned* __restrict__ pdeg,
        float* __restrict__ dinv, float* __restrict__ xs) {
    const int t = blockIdx.x * TRD + threadIdx.x;
    const int g0 = 2 * t;
    if (g0 >= N_NODES) return;
    const int bu = g0 / BN, l = g0 - bu * BN;      // l even (BN even)
    const unsigned* pp = pdeg + (size_t)(bu * DSL) * BNH + (l >> 1);
    unsigned r0 = 0, r1 = 0;
    #pragma unroll
    for (int s = 0; s < DSL; ++s) {
        const unsigned w = pp[(size_t)s * BNH];
        r0 += w & 0xFFFFu; r1 += w >> 16;
    }
    const float di0 = rsqrtf((float)r0 + 1.f);     // + self loop
    const float di1 = rsqrtf((float)r1 + 1.f);
    const float2 xv = *(const float2*)(x + g0);
    *(float2*)(dinv + g0) = make_float2(di0, di1);
    *(float2*)(xs + g0)   = make_float2(xv.x * di0, xv.y * di1);
}

// ---- K4: layer1 + folded layer2 weights -> us, uself ------------------------
__global__ __launch_bounds__(TRD) void k_red2(const float* __restrict__ x,
        const float* __restrict__ partials, const float* __restrict__ dinv,
        const float* __restrict__ W1, const float* __restrict__ b1,
        const float* __restrict__ W2, const float* __restrict__ Wl,
        float* __restrict__ us, float* __restrict__ uself) {
    const int g = blockIdx.x * TRD + threadIdx.x;
    if (g >= N_NODES) return;
    const float sum = sum_partials(partials, g);
    const float di = dinv[g];
    const float s1 = di * sum + x[g] * di * di;
    float u = 0.f;
    #pragma unroll
    for (int c = 0; c < 16; ++c) {
        float vcc = 0.f;
        #pragma unroll
        for (int k = 0; k < 16; ++k) vcc += W2[c * 16 + k] * Wl[k];  // (W2@Wl)[c]
        u += fmaxf(W1[c] * s1 + b1[c], 0.f) * vcc;
    }
    us[g] = u * di;
    uself[g] = u * di * di;
}

// ---- K6: epilogue -----------------------------------------------------------
__global__ __launch_bounds__(TRD) void k_red3(const float* __restrict__ partials,
        const float* __restrict__ dinv, const float* __restrict__ uself,
        const float* __restrict__ W2, const float* __restrict__ b2,
        const float* __restrict__ Wl, const float* __restrict__ bl,
        float* __restrict__ out) {
    const int g = blockIdx.x * TRD + threadIdx.x;
    if (g >= N_NODES) return;
    const float sum = sum_partials(partials, g);
    float vcb = bl[0];
    #pragma unroll
    for (int c = 0; c < 16; ++c) {
        float vcc = 0.f;
        #pragma unroll
        for (int k = 0; k < 16; ++k) vcc += W2[c * 16 + k] * Wl[k];
        vcb += b2[c] * vcc;
    }
    out[g] = dinv[g] * sum + uself[g] + vcb;
}

extern "C" void kernel_launch(void* const* d_in, const int* in_sizes, int n_in,
                              void* d_out, int out_size, void* d_ws, size_t ws_size,
                              hipStream_t stream) {
    const float* x  = (const float*)d_in[0];
    const int*   ei = (const int*)d_in[1];
    const float* W1 = (const float*)d_in[2];
    const float* b1 = (const float*)d_in[3];
    const float* W2 = (const float*)d_in[4];
    const float* b2 = (const float*)d_in[5];
    const float* Wl = (const float*)d_in[6];
    const float* bl = (const float*)d_in[7];
    float* out = (float*)d_out;

    unsigned* cnt      = (unsigned*)d_ws;
    unsigned* pedge    = cnt + NRT * NB;
    float*    partials = (float*)(pedge + (size_t)NRT * NB * CAP);
    unsigned* pdeg     = (unsigned*)(partials + (size_t)GA * BN);
    float*    dinv     = (float*)(pdeg + (size_t)NDG * BNH);
    float*    xs       = dinv + N_NODES;
    float*    us       = xs + N_NODES;
    float*    uself    = us + N_NODES;

    const int rb1 = (N_NODES / 2 + TRD - 1) / TRD;   // 196
    const int rb  = (N_NODES + TRD - 1) / TRD;       // 391

    k_route_deg<<<NDG + NRT, THR, 0, stream>>>(ei, cnt, pedge, pdeg);
    k_red1 <<<rb1, TRD, 0, stream>>>(x, pdeg, dinv, xs);
    k_acc  <<<GA,  THR, 0, stream>>>(pedge, cnt, xs, partials);
    k_red2 <<<rb,  TRD, 0, stream>>>(x, partials, dinv, W1, b1, W2, Wl, us, uself);
    k_acc  <<<GA,  THR, 0, stream>>>(pedge, cnt, us, partials);
    k_red3 <<<rb,  TRD, 0, stream>>>(partials, dinv, uself, W2, b2, Wl, bl, out);
}

// Round 4
// 188.483 us; speedup vs baseline: 1.9001x; 1.0057x over previous
//
#include <hip/hip_runtime.h>

#define N_NODES  100000
#define N_EDGES  3200000
#define NB       8                    // buckets
#define BN       12544                // nodes per bucket (8*12544 >= 100000)
#define BNH      (BN / 2)             // 6272 packed u16-pair words
#define NRT      256                  // routing blocks
#define DSL      32                   // degree slices per bucket
#define NDG      (NB * DSL)           // 256 degree blocks
#define THR      1024
#define QPB      (N_EDGES / NRT / 4)  // 3125 uint4 quads per routing block
#define QDS      (N_EDGES / DSL / 4)  // 25000 quads per degree slice
#define CAP      2048                 // per (block,bucket) region cap (mean 1562, sigma 37)
#define SA       32                   // acc blocks per bucket
#define SPS      (NRT / SA)           // 8 routing-block regions per acc block
#define GA       (NB * SA)            // 256 acc blocks
#define TRD      256                  // reduction block size

// ws (u32 words): cnt[NRT*NB] | pedge[NRT*NB*CAP] | partials f32[GA*BN]
//                 | pdeg u32[NDG*BNH] | dinv[N] | xs[N] | us[N] | uself[N]

// ---- K1: interleaved roles: single-read routing + dst-degree histograms ----
//      even blocks: degree histogram of one dst slice for one bucket
//      odd  blocks: bucket-route one edge slice (count->prefix->place->flush)
__global__ __launch_bounds__(THR) void k_route_deg(
        const int* __restrict__ ei, unsigned* __restrict__ cnt,
        unsigned* __restrict__ pedge, unsigned* __restrict__ pdeg) {
    __shared__ __align__(16) unsigned smem[BN];   // stag (route) / packed hist (deg)
    __shared__ unsigned bcnt[NB], bbase[NB], bcur[NB];
    const int tid = threadIdx.x;
    const int idx = blockIdx.x >> 1;
    const uint4* d4 = (const uint4*)(ei + N_EDGES);

    if ((blockIdx.x & 1) == 0) {
        // ---- degree role: u16-packed histogram, slice s of bucket bu -------
        const int bu = idx >> 5, s = idx & 31;    // idx == bu*DSL + s
        for (int i = tid; i < BNH; i += THR) smem[i] = 0u;
        __syncthreads();
        const unsigned base_node = (unsigned)bu * BN;
        const int q1 = (s + 1) * QDS;
        #pragma unroll 2
        for (int q = s * QDS + tid; q < q1; q += THR) {
            const uint4 dv = d4[q];
            const unsigned dd[4] = { dv.x, dv.y, dv.z, dv.w };
            #pragma unroll
            for (int k = 0; k < 4; ++k) {
                const unsigned dl = dd[k] - base_node;   // unsigned wrap if below
                if (dl < BN)
                    atomicAdd(&smem[dl >> 1], 1u << ((dl & 1) << 4));
            }
        }
        __syncthreads();
        uint4* po = (uint4*)(pdeg + (size_t)idx * BNH);
        const uint4* fi = (const uint4*)smem;
        for (int i = tid; i < BNH / 4; i += THR) po[i] = fi[i];
        return;
    }

    // ---- routing role --------------------------------------------------------
    const int blk = idx;
    if (tid < NB) bcnt[tid] = 0u;
    __syncthreads();

    const uint4* s4 = (const uint4*)ei;
    const int q0 = blk * QPB;
    uint4 dq[4], sq[4];
    #pragma unroll
    for (int i = 0; i < 4; ++i) {
        const int q = tid + i * THR;
        if (q < QPB) { dq[i] = d4[q0 + q]; sq[i] = s4[q0 + q]; }
    }

    unsigned c01 = 0, c23 = 0;   // byte-packed per-thread bucket histogram
    #pragma unroll
    for (int i = 0; i < 4; ++i) {
        const int q = tid + i * THR;
        if (q < QPB) {
            const unsigned dd[4] = { dq[i].x, dq[i].y, dq[i].z, dq[i].w };
            #pragma unroll
            for (int k = 0; k < 4; ++k) {
                const unsigned b = dd[k] / BN;
                if (b < 4) c01 += 1u << (8 * b);
                else       c23 += 1u << (8 * (b - 4));
            }
        }
    }
    #pragma unroll
    for (int b = 0; b < 4; ++b) {
        const unsigned v0 = (c01 >> (8 * b)) & 0xFFu;
        const unsigned v1 = (c23 >> (8 * b)) & 0xFFu;
        if (v0) atomicAdd(&bcnt[b], v0);
        if (v1) atomicAdd(&bcnt[b + 4], v1);
    }
    __syncthreads();
    if (tid == 0) {
        unsigned run = 0;
        #pragma unroll
        for (int b = 0; b < NB; ++b) { bbase[b] = run; bcur[b] = run; run += bcnt[b]; }
    }
    __syncthreads();

    #pragma unroll
    for (int i = 0; i < 4; ++i) {
        const int q = tid + i * THR;
        if (q < QPB) {
            const unsigned dd[4] = { dq[i].x, dq[i].y, dq[i].z, dq[i].w };
            const unsigned ss[4] = { sq[i].x, sq[i].y, sq[i].z, sq[i].w };
            #pragma unroll
            for (int k = 0; k < 4; ++k) {
                const unsigned d = dd[k];
                const unsigned b = d / BN;
                const unsigned slot = atomicAdd(&bcur[b], 1u);
                smem[slot] = ss[k] | ((d - b * BN) << 17);   // total 12500 < BN
            }
        }
    }
    __syncthreads();

    #pragma unroll
    for (int b = 0; b < NB; ++b) {
        const unsigned n = bcnt[b] < CAP ? bcnt[b] : CAP;
        const unsigned base = bbase[b];
        unsigned* reg = pedge + ((size_t)(blk * NB + b)) * CAP;
        for (unsigned j = tid; j < n; j += THR) reg[j] = smem[base + j];
    }
    if (tid < NB) cnt[blk * NB + tid] = bcnt[tid] < CAP ? bcnt[tid] : CAP;
}

// ---- K3/K5: scatter one value-class into LDS bucket image (ILP-4 gathers) --
__global__ __launch_bounds__(THR) void k_acc(
        const unsigned* __restrict__ pedge, const unsigned* __restrict__ cnt,
        const float* __restrict__ vals, float* __restrict__ partials) {
    __shared__ __align__(16) float facc[BN];
    const int tid = threadIdx.x;
    const int bu = blockIdx.x / SA, sub = blockIdx.x % SA;
    for (int i = tid; i < BN / 4; i += THR)
        ((float4*)facc)[i] = make_float4(0.f, 0.f, 0.f, 0.f);
    __syncthreads();
    for (int s = 0; s < SPS; ++s) {
        const int r = (sub * SPS + s) * NB + bu;
        const unsigned n = cnt[r];
        const unsigned* reg = pedge + (size_t)r * CAP;
        const uint4* reg4 = (const uint4*)reg;
        const unsigned n4 = n >> 2;
        for (unsigned j = tid; j < n4; j += THR) {
            const uint4 w = reg4[j];
            const float v0 = vals[w.x & 0x1FFFFu];
            const float v1 = vals[w.y & 0x1FFFFu];
            const float v2 = vals[w.z & 0x1FFFFu];
            const float v3 = vals[w.w & 0x1FFFFu];
            atomicAdd(&facc[w.x >> 17], v0);
            atomicAdd(&facc[w.y >> 17], v1);
            atomicAdd(&facc[w.z >> 17], v2);
            atomicAdd(&facc[w.w >> 17], v3);
        }
        for (unsigned j = (n4 << 2) + tid; j < n; j += THR) {
            const unsigned w = reg[j];
            atomicAdd(&facc[w >> 17], vals[w & 0x1FFFFu]);
        }
    }
    __syncthreads();
    float4* po = (float4*)(partials + (size_t)blockIdx.x * BN);
    const float4* fi = (const float4*)facc;
    for (int i = tid; i < BN / 4; i += THR) po[i] = fi[i];
}

// ---- f32 partial reduction (SA slices, coalesced) ---------------------------
__device__ __forceinline__ float sum_partials(const float* __restrict__ partials,
                                              int g) {
    const int bu = g / BN, l = g - bu * BN;
    const float* pp = partials + (size_t)(bu * SA) * BN + l;
    float s = 0.f;
    #pragma unroll
    for (int k = 0; k < SA; ++k) s += pp[(size_t)k * BN];
    return s;
}

// ---- K2: packed u16 deg partials -> dinv, xs (2 nodes/thread) --------------
__global__ __launch_bounds__(TRD) void k_red1(const float* __restrict__ x,
        const unsigned* __restrict__ pdeg,
        float* __restrict__ dinv, float* __restrict__ xs) {
    const int t = blockIdx.x * TRD + threadIdx.x;
    const int g0 = 2 * t;
    if (g0 >= N_NODES) return;
    const int bu = g0 / BN, l = g0 - bu * BN;      // l even (BN even)
    const unsigned* pp = pdeg + (size_t)(bu * DSL) * BNH + (l >> 1);
    unsigned r0 = 0, r1 = 0;
    #pragma unroll
    for (int s = 0; s < DSL; ++s) {
        const unsigned w = pp[(size_t)s * BNH];
        r0 += w & 0xFFFFu; r1 += w >> 16;
    }
    const float di0 = rsqrtf((float)r0 + 1.f);     // + self loop
    const float di1 = rsqrtf((float)r1 + 1.f);
    const float2 xv = *(const float2*)(x + g0);
    *(float2*)(dinv + g0) = make_float2(di0, di1);
    *(float2*)(xs + g0)   = make_float2(xv.x * di0, xv.y * di1);
}

// ---- K4: layer1 + folded layer2 weights -> us, uself ------------------------
__global__ __launch_bounds__(TRD) void k_red2(const float* __restrict__ x,
        const float* __restrict__ partials, const float* __restrict__ dinv,
        const float* __restrict__ W1, const float* __restrict__ b1,
        const float* __restrict__ W2, const float* __restrict__ Wl,
        float* __restrict__ us, float* __restrict__ uself) {
    const int g = blockIdx.x * TRD + threadIdx.x;
    if (g >= N_NODES) return;
    const float sum = sum_partials(partials, g);
    const float di = dinv[g];
    const float s1 = di * sum + x[g] * di * di;
    float u = 0.f;
    #pragma unroll
    for (int c = 0; c < 16; ++c) {
        float vcc = 0.f;
        #pragma unroll
        for (int k = 0; k < 16; ++k) vcc += W2[c * 16 + k] * Wl[k];  // (W2@Wl)[c]
        u += fmaxf(W1[c] * s1 + b1[c], 0.f) * vcc;
    }
    us[g] = u * di;
    uself[g] = u * di * di;
}

// ---- K6: epilogue -----------------------------------------------------------
__global__ __launch_bounds__(TRD) void k_red3(const float* __restrict__ partials,
        const float* __restrict__ dinv, const float* __restrict__ uself,
        const float* __restrict__ W2, const float* __restrict__ b2,
        const float* __restrict__ Wl, const float* __restrict__ bl,
        float* __restrict__ out) {
    const int g = blockIdx.x * TRD + threadIdx.x;
    if (g >= N_NODES) return;
    const float sum = sum_partials(partials, g);
    float vcb = bl[0];
    #pragma unroll
    for (int c = 0; c < 16; ++c) {
        float vcc = 0.f;
        #pragma unroll
        for (int k = 0; k < 16; ++k) vcc += W2[c * 16 + k] * Wl[k];
        vcb += b2[c] * vcc;
    }
    out[g] = dinv[g] * sum + uself[g] + vcb;
}

extern "C" void kernel_launch(void* const* d_in, const int* in_sizes, int n_in,
                              void* d_out, int out_size, void* d_ws, size_t ws_size,
                              hipStream_t stream) {
    const float* x  = (const float*)d_in[0];
    const int*   ei = (const int*)d_in[1];
    const float* W1 = (const float*)d_in[2];
    const float* b1 = (const float*)d_in[3];
    const float* W2 = (const float*)d_in[4];
    const float* b2 = (const float*)d_in[5];
    const float* Wl = (const float*)d_in[6];
    const float* bl = (const float*)d_in[7];
    float* out = (float*)d_out;

    unsigned* cnt      = (unsigned*)d_ws;
    unsigned* pedge    = cnt + NRT * NB;
    float*    partials = (float*)(pedge + (size_t)NRT * NB * CAP);
    unsigned* pdeg     = (unsigned*)(partials + (size_t)GA * BN);
    float*    dinv     = (float*)(pdeg + (size_t)NDG * BNH);
    float*    xs       = dinv + N_NODES;
    float*    us       = xs + N_NODES;
    float*    uself    = us + N_NODES;

    const int rb1 = (N_NODES / 2 + TRD - 1) / TRD;   // 196
    const int rb  = (N_NODES + TRD - 1) / TRD;       // 391

    k_route_deg<<<NDG + NRT, THR, 0, stream>>>(ei, cnt, pedge, pdeg);
    k_red1 <<<rb1, TRD, 0, stream>>>(x, pdeg, dinv, xs);
    k_acc  <<<GA,  THR, 0, stream>>>(pedge, cnt, xs, partials);
    k_red2 <<<rb,  TRD, 0, stream>>>(x, partials, dinv, W1, b1, W2, Wl, us, uself);
    k_acc  <<<GA,  THR, 0, stream>>>(pedge, cnt, us, partials);
    k_red3 <<<rb,  TRD, 0, stream>>>(partials, dinv, uself, W2, b2, Wl, bl, out);
}